// Round 1
// baseline (31.240 us; speedup 1.0000x reference)
//
#include <hip/hip_runtime.h>
#include <math.h>

#define T_STEPS 1000000
#define BLOCK 256
#define ITEMS 4
#define CHUNK (BLOCK * ITEMS)
#define NB ((T_STEPS + CHUNK - 1) / CHUNK)  // 977

// ---- block-wide helpers (fp64, LDS) ------------------------------------

__device__ __forceinline__ double blockReduceSum(double v, double* s) {
    const int t = threadIdx.x;
    s[t] = v;
    __syncthreads();
#pragma unroll
    for (int off = BLOCK / 2; off > 0; off >>= 1) {
        if (t < off) s[t] += s[t + off];
        __syncthreads();
    }
    double r = s[0];
    __syncthreads();
    return r;
}

__device__ __forceinline__ double blockExclScan(double v, double* s) {
    const int t = threadIdx.x;
    s[t] = v;
    __syncthreads();
#pragma unroll
    for (int off = 1; off < BLOCK; off <<= 1) {
        double x = (t >= off) ? s[t - off] : 0.0;
        __syncthreads();
        s[t] += x;
        __syncthreads();
    }
    double ex = (t > 0) ? s[t - 1] : 0.0;
    __syncthreads();
    return ex;
}

// ---- K1: copy controls to out, per-block sums of dtheta -----------------

__global__ void k_sum_dth(const float2* __restrict__ ctrl,
                          float2* __restrict__ ctrl_out,
                          double* __restrict__ bsumTh) {
    __shared__ double sred[BLOCK];
    const int b = blockIdx.x, t = threadIdx.x;
    const long base = (long)b * CHUNK;
    double s = 0.0;
#pragma unroll
    for (int it = 0; it < ITEMS; ++it) {
        long i = base + (long)it * BLOCK + t;  // striped: coalesced
        if (i < T_STEPS) {
            float2 c = ctrl[i];
            ctrl_out[i] = c;
            s += (double)c.y;
        }
    }
    double tot = blockReduceSum(s, sred);
    if (t == 0) bsumTh[b] = 10.0 * tot;
}

// ---- K2: theta scan, dx/dy, per-block dx/dy sums ------------------------
// Writes (dx, dy, theta) as fp32 into traj rows 1..T (used as scratch).

__global__ void k_theta_dxdy(const float2* __restrict__ ctrl,
                             const float* __restrict__ start_pose,
                             const double* __restrict__ bsumTh,
                             float* __restrict__ traj,
                             double* __restrict__ bsumX,
                             double* __restrict__ bsumY) {
    __shared__ double sred[BLOCK];
    const int b = blockIdx.x, t = threadIdx.x;
    const long base = (long)b * CHUNK;

    // this block's theta offset = sum of all previous block sums
    double p = 0.0;
    for (int i = t; i < b; i += BLOCK) p += bsumTh[i];
    const double thOff = blockReduceSum(p, sred);

    // blocked load: thread owns ITEMS contiguous elements (32B/lane)
    const long e0 = base + (long)t * ITEMS;
    float2 c[ITEMS];
#pragma unroll
    for (int k = 0; k < ITEMS; ++k) {
        long i = e0 + k;
        c[k] = (i < T_STEPS) ? ctrl[i] : make_float2(0.f, 0.f);
    }

    double dth[ITEMS];
    double lsum = 0.0;
#pragma unroll
    for (int k = 0; k < ITEMS; ++k) {
        dth[k] = 10.0 * (double)c[k].y;
        lsum += dth[k];
    }
    const double ex = blockExclScan(lsum, sred);

    const double th0 = (double)start_pose[2];
    double run = th0 + thOff + ex;  // theta BEFORE first owned element
    double sx = 0.0, sy = 0.0;
#pragma unroll
    for (int k = 0; k < ITEMS; ++k) {
        const double thp = run;   // theta_prev for element i
        run += dth[k];            // theta at step i+1
        long i = e0 + k;
        if (i < T_STEPS) {
            double sv, cv;
            sincos(thp, &sv, &cv);
            const double sp  = fabs((double)c[k].x);
            const double dxv = sp * cv;
            const double dyv = sp * sv;
            sx += dxv;
            sy += dyv;
            float* row = traj + 3 * (i + 1);
            row[0] = (float)dxv;
            row[1] = (float)dyv;
            row[2] = (float)run;
        }
    }
    double totX = blockReduceSum(sx, sred);
    double totY = blockReduceSum(sy, sred);
    if (t == 0) {
        bsumX[b] = totX;
        bsumY[b] = totY;
    }
    if (b == 0 && t == 0) {
        traj[0] = start_pose[0];
        traj[1] = start_pose[1];
        traj[2] = start_pose[2];
    }
}

// ---- K3: finish x/y scans in place --------------------------------------

__global__ void k_final(const float* __restrict__ start_pose,
                        const double* __restrict__ bsumX,
                        const double* __restrict__ bsumY,
                        float* __restrict__ traj) {
    __shared__ double sred[BLOCK];
    const int b = blockIdx.x, t = threadIdx.x;
    const long base = (long)b * CHUNK;

    double px = 0.0, py = 0.0;
    for (int i = t; i < b; i += BLOCK) {
        px += bsumX[i];
        py += bsumY[i];
    }
    const double xOff = blockReduceSum(px, sred);
    const double yOff = blockReduceSum(py, sred);

    const long e0 = base + (long)t * ITEMS;
    double dxv[ITEMS], dyv[ITEMS];
    double lsx = 0.0, lsy = 0.0;
#pragma unroll
    for (int k = 0; k < ITEMS; ++k) {
        long i = e0 + k;
        if (i < T_STEPS) {
            const float* row = traj + 3 * (i + 1);
            dxv[k] = (double)row[0];
            dyv[k] = (double)row[1];
        } else {
            dxv[k] = 0.0;
            dyv[k] = 0.0;
        }
        lsx += dxv[k];
        lsy += dyv[k];
    }
    const double exx = blockExclScan(lsx, sred);
    const double exy = blockExclScan(lsy, sred);

    double rx = (double)start_pose[0] + xOff + exx;
    double ry = (double)start_pose[1] + yOff + exy;
#pragma unroll
    for (int k = 0; k < ITEMS; ++k) {
        rx += dxv[k];
        ry += dyv[k];
        long i = e0 + k;
        if (i < T_STEPS) {
            float* row = traj + 3 * (i + 1);
            row[0] = (float)rx;
            row[1] = (float)ry;
            // row[2] (theta) already written by K2
        }
    }
}

// ---- launch --------------------------------------------------------------

extern "C" void kernel_launch(void* const* d_in, const int* in_sizes, int n_in,
                              void* d_out, int out_size, void* d_ws, size_t ws_size,
                              hipStream_t stream) {
    const float*  start_pose = (const float*)d_in[0];
    const float2* ctrl       = (const float2*)d_in[1];

    float*  out      = (float*)d_out;
    float2* ctrl_out = (float2*)out;
    float*  traj     = out + 2 * (long)T_STEPS;

    double* bsumTh = (double*)d_ws;
    double* bsumX  = bsumTh + NB;
    double* bsumY  = bsumX + NB;

    hipLaunchKernelGGL(k_sum_dth, dim3(NB), dim3(BLOCK), 0, stream,
                       ctrl, ctrl_out, bsumTh);
    hipLaunchKernelGGL(k_theta_dxdy, dim3(NB), dim3(BLOCK), 0, stream,
                       ctrl, start_pose, bsumTh, traj, bsumX, bsumY);
    hipLaunchKernelGGL(k_final, dim3(NB), dim3(BLOCK), 0, stream,
                       start_pose, bsumX, bsumY, traj);
}